// Round 5
// baseline (101.556 us; speedup 1.0000x reference)
//
#include <hip/hip_runtime.h>
#include <hip/hip_bf16.h>
#include <math.h>

// Sizes (fixed): B=256, VIS=1024, BOT=64, CTX=512, H=16, MLP_H=4
#define B_SZ   256
#define VIS    1024
#define BOT    64
#define CTX    512
#define KH     16
#define MLP_H  4

// ---------------------------------------------------------------------------
// kA: z = x @ reduce_w + reduce_b (written transposed zT[i*256+b]);
//     a4 = relu(z @ ann_w1 + ann_b1).
// 256 blocks x 512 threads (8 waves). Wave w = k-chunk of 128; lane: kq=l>>4
// (k-subchunk of 32), jq=l&15 (j-quad, float4 rw loads). Per thread: 32
// float4 loads, 4 independent FMA chains; shfl-xor reduce over kq.
// ---------------------------------------------------------------------------
__global__ __launch_bounds__(512) void kA(
    const float* __restrict__ x,
    const float* __restrict__ rw,
    const float* __restrict__ rb,
    const float* __restrict__ aw1,
    const float* __restrict__ ab1,
    float* __restrict__ zT,
    float* __restrict__ a4)
{
    const int b = blockIdx.x;
    const int t = threadIdx.x;
    const int w = t >> 6, l = t & 63;
    const int kq = l >> 4, jq = l & 15;
    const int kbase = w * 128 + kq * 32;

    const float*  __restrict__ xb = x + (size_t)b * VIS + kbase;
    const float4* __restrict__ wb = (const float4*)rw + (size_t)kbase * 16 + jq;

    float4 a = make_float4(0.f, 0.f, 0.f, 0.f);
#pragma unroll 8
    for (int tt = 0; tt < 32; ++tt) {
        const float  xv = xb[tt];                 // 4 bcast addrs/wave
        const float4 wv = wb[(size_t)tt * 16];    // 1KB/wave coalesced
        a.x = fmaf(xv, wv.x, a.x);
        a.y = fmaf(xv, wv.y, a.y);
        a.z = fmaf(xv, wv.z, a.z);
        a.w = fmaf(xv, wv.w, a.w);
    }
    // reduce over the 4 k-subchunks (lanes xor 16, 32)
    a.x += __shfl_xor(a.x, 16, 64); a.y += __shfl_xor(a.y, 16, 64);
    a.z += __shfl_xor(a.z, 16, 64); a.w += __shfl_xor(a.w, 16, 64);
    a.x += __shfl_xor(a.x, 32, 64); a.y += __shfl_xor(a.y, 32, 64);
    a.z += __shfl_xor(a.z, 32, 64); a.w += __shfl_xor(a.w, 32, 64);

    __shared__ float4 zp[8][16];   // [wave][jq] -> j = jq*4..jq*4+3
    __shared__ float  zs[64];
    if (l < 16) zp[w][jq] = a;
    __syncthreads();

    if (t < BOT) {
        const float* z0 = (const float*)&zp[0][0];   // [w*64 + j]
        float z = rb[t];
#pragma unroll
        for (int wq = 0; wq < 8; ++wq) z += z0[wq * 64 + t];
        zs[t] = z;
        zT[(size_t)t * B_SZ + b] = z;   // transposed: i-major
    }
    __syncthreads();

    if (t < MLP_H) {
        float s = ab1[t];
#pragma unroll
        for (int i = 0; i < BOT; ++i) s = fmaf(zs[i], aw1[i * MLP_H + t], s);
        a4[b * MLP_H + t] = fmaxf(s, 0.f);
    }
}

// ---------------------------------------------------------------------------
// k2: KAN + gate + epilogue. 512 blocks x 512 threads (8 waves).
// Block tile: 16 o x 16 b; wave w = i-chunk of 8. Lane: o_l=l>>2, hq=l&3.
// z-tile (64 i x 16 b, 4KB) staged in LDS once via float4 (FIXED: R4 only
// staged i=0..15); inner loop reads z via ds_read_b128 broadcast. Weights:
// lane-contiguous float4 loads. h-reduce via shfl_xor. Gate dot + kb2/gw
// column sums in the epilogue from the LDS z-tile.
// ---------------------------------------------------------------------------
__global__ __launch_bounds__(512) void k2_main(
    const float* __restrict__ zT,
    const float* __restrict__ a4,
    const float* __restrict__ aw2,
    const float* __restrict__ ab2,
    const float* __restrict__ kW1,
    const float* __restrict__ kb1,
    const float* __restrict__ kW2,
    const float* __restrict__ kb2,
    const float* __restrict__ gw,
    const float* __restrict__ gb,
    float* __restrict__ out)
{
    __shared__ float zl[BOT][16];        // z-tile: [i][b], 4KB, broadcast reads
    __shared__ float pK[8][16][24];      // [wave][o][b], padded rows

    const int t    = threadIdx.x;
    const int w    = t >> 6;
    const int lane = t & 63;
    const int o_l  = lane >> 2;
    const int hq   = lane & 3;
    const int o0   = blockIdx.x * 16;
    const int b0   = blockIdx.y * 16;

    // stage full z-tile: 256 threads x one float4 = 64 i-rows x 4 quads.
    if (t < 256) {
        const int i = t >> 2, q = t & 3;
        ((float4*)&zl[i][0])[q] =
            ((const float4*)(zT + (size_t)i * B_SZ + b0))[q];
    }
    __syncthreads();

    float4 acc[16];
#pragma unroll
    for (int b = 0; b < 16; ++b) acc[b] = make_float4(0.f, 0.f, 0.f, 0.f);

    const int i0 = w * 8;
#pragma unroll 2
    for (int ii = 0; ii < 8; ++ii) {
        const int i = i0 + ii;
        const size_t wbo = ((size_t)i * CTX + o0) * KH + (size_t)lane * 4;
        const float4 w1 = *(const float4*)(kW1 + wbo);
        const float4 b1 = *(const float4*)(kb1 + wbo);
        const float4 w2 = *(const float4*)(kW2 + wbo);
        const float4* zr = (const float4*)&zl[i][0];   // LDS broadcast
        const float4 za = zr[0], zb = zr[1], zc = zr[2], zd = zr[3];
        const float zv[16] = { za.x, za.y, za.z, za.w,  zb.x, zb.y, zb.z, zb.w,
                               zc.x, zc.y, zc.z, zc.w,  zd.x, zd.y, zd.z, zd.w };
#pragma unroll
        for (int b = 0; b < 16; ++b) {
            const float z = zv[b];
            float4 hv;
            hv.x = fmaxf(fmaf(z, w1.x, b1.x), 0.f);
            hv.y = fmaxf(fmaf(z, w1.y, b1.y), 0.f);
            hv.z = fmaxf(fmaf(z, w1.z, b1.z), 0.f);
            hv.w = fmaxf(fmaf(z, w1.w, b1.w), 0.f);
            acc[b].x = fmaf(hv.x, w2.x, acc[b].x);
            acc[b].y = fmaf(hv.y, w2.y, acc[b].y);
            acc[b].z = fmaf(hv.z, w2.z, acc[b].z);
            acc[b].w = fmaf(hv.w, w2.w, acc[b].w);
        }
    }

    // in-lane h-quad sum, then shfl-xor reduce across the 4 hq lanes
    float aK[16];
#pragma unroll
    for (int b = 0; b < 16; ++b) {
        float s = (acc[b].x + acc[b].y) + (acc[b].z + acc[b].w);
        s += __shfl_xor(s, 1, 64);
        s += __shfl_xor(s, 2, 64);
        aK[b] = s;
    }
    if (hq == 0) {
        float* d = &pK[w][o_l][0];
        ((float4*)d)[0] = make_float4(aK[0],  aK[1],  aK[2],  aK[3]);
        ((float4*)d)[1] = make_float4(aK[4],  aK[5],  aK[6],  aK[7]);
        ((float4*)d)[2] = make_float4(aK[8],  aK[9],  aK[10], aK[11]);
        ((float4*)d)[3] = make_float4(aK[12], aK[13], aK[14], aK[15]);
    }
    __syncthreads();

    // epilogue: t<256 -> (o = t&15, b = t>>4); gate dot + column sums here.
    if (t < 256) {
        const int o = t & 15;
        const int b = t >> 4;
        const int oo = o0 + o;
        const int bb = b0 + b;

        float sK = 0.f;
#pragma unroll
        for (int w2 = 0; w2 < 8; ++w2) sK += pK[w2][o][b];

        float sG = 0.f, sKB = 0.f;
#pragma unroll 8
        for (int i = 0; i < BOT; ++i) {
            const float zi = zl[i][b];               // LDS broadcast
            sG  = fmaf(zi + 1.f, gw[i * CTX + oo], sG);
            sKB += kb2[i * CTX + oo];
        }
        sK += sKB;
        sG += gb[oo];

        const float4 av = *(const float4*)(a4 + bb * MLP_H);
        float ann = ab2[oo];
        ann = fmaf(av.x, aw2[0 * CTX + oo], ann);
        ann = fmaf(av.y, aw2[1 * CTX + oo], ann);
        ann = fmaf(av.z, aw2[2 * CTX + oo], ann);
        ann = fmaf(av.w, aw2[3 * CTX + oo], ann);

        const float g = 1.f / (1.f + __expf(-sG));
        out[(size_t)bb * CTX + oo] = g * ann + (1.f - g) * sK;
    }
}

extern "C" void kernel_launch(void* const* d_in, const int* in_sizes, int n_in,
                              void* d_out, int out_size, void* d_ws, size_t ws_size,
                              hipStream_t stream)
{
    const float* x   = (const float*)d_in[0];
    const float* rw  = (const float*)d_in[1];
    const float* rb  = (const float*)d_in[2];
    const float* aw1 = (const float*)d_in[3];
    const float* ab1 = (const float*)d_in[4];
    const float* aw2 = (const float*)d_in[5];
    const float* ab2 = (const float*)d_in[6];
    const float* kW1 = (const float*)d_in[7];
    const float* kb1 = (const float*)d_in[8];
    const float* kW2 = (const float*)d_in[9];
    const float* kb2 = (const float*)d_in[10];
    const float* gw  = (const float*)d_in[11];
    const float* gb  = (const float*)d_in[12];
    float* out = (float*)d_out;

    // ws layout: zT (64*256 f32) | a4 (256*4 f32)
    float* zT = (float*)d_ws;
    float* a4 = zT + (size_t)BOT * B_SZ;

    kA<<<B_SZ, 512, 0, stream>>>(x, rw, rb, aw1, ab1, zT, a4);
    k2_main<<<dim3(CTX / 16, B_SZ / 16), 512, 0, stream>>>(
        zT, a4, aw2, ab2, kW1, kb1, kW2, kb2, gw, gb, out);
}

// Round 6
// 100.498 us; speedup vs baseline: 1.0105x; 1.0105x over previous
//
#include <hip/hip_runtime.h>
#include <hip/hip_bf16.h>
#include <math.h>

// Sizes (fixed): B=256, VIS=1024, BOT=64, CTX=512, H=16, MLP_H=4
#define B_SZ   256
#define VIS    1024
#define BOT    64
#define CTX    512
#define KH     16
#define MLP_H  4

// ---------------------------------------------------------------------------
// kA: blocks 0..255: z = x @ reduce_w + reduce_b (transposed zT[i*256+b]) and
//     a4 = relu(z @ ann_w1 + ann_b1).  Blocks 256..263 (piggyback, run
//     concurrently): kb2s[o] = sum_i kan_b2[i,o], gwsum[o] = sum_i gate_w[i,o]
//     (folds the gate "+1": (z+1)@gw = z@gw + gwsum).
// z-part: 512 threads (8 waves). Wave w = k-chunk of 128; lane: kq=l>>4
// (k-subchunk of 32), jq=l&15 (j-quad, float4 rw loads). 4 independent FMA
// chains/thread; shfl-xor reduce over kq.
// ---------------------------------------------------------------------------
__global__ __launch_bounds__(512) void kA(
    const float* __restrict__ x,
    const float* __restrict__ rw,
    const float* __restrict__ rb,
    const float* __restrict__ aw1,
    const float* __restrict__ ab1,
    const float* __restrict__ kb2,
    const float* __restrict__ gw,
    float* __restrict__ zT,
    float* __restrict__ a4,
    float* __restrict__ kb2s,
    float* __restrict__ gwsum)
{
    const int t = threadIdx.x;

    if (blockIdx.x >= B_SZ) {
        // ---- presum: 8 blocks x 64 o; waves over i-chunks of 8 ----
        __shared__ float r0[8][64], r1[8][64];
        const int blk = blockIdx.x - B_SZ;
        const int w = t >> 6, l = t & 63;
        const int o = blk * 64 + l;
        float s0 = 0.f, s1 = 0.f;
#pragma unroll
        for (int ii = 0; ii < 8; ++ii) {
            const int i = w * 8 + ii;
            s0 += kb2[i * CTX + o];     // coalesced 256B/wave
            s1 += gw[i * CTX + o];
        }
        r0[w][l] = s0; r1[w][l] = s1;
        __syncthreads();
        if (t < 64) {
            float a0 = 0.f, a1 = 0.f;
#pragma unroll
            for (int wq = 0; wq < 8; ++wq) { a0 += r0[wq][t]; a1 += r1[wq][t]; }
            kb2s[blk * 64 + t]  = a0;
            gwsum[blk * 64 + t] = a1;
        }
        return;
    }

    // ---- z part ----
    const int b = blockIdx.x;
    const int w = t >> 6, l = t & 63;
    const int kq = l >> 4, jq = l & 15;
    const int kbase = w * 128 + kq * 32;

    const float*  __restrict__ xb = x + (size_t)b * VIS + kbase;
    const float4* __restrict__ wb = (const float4*)rw + (size_t)kbase * 16 + jq;

    float4 a = make_float4(0.f, 0.f, 0.f, 0.f);
#pragma unroll 8
    for (int tt = 0; tt < 32; ++tt) {
        const float  xv = xb[tt];                 // 4 bcast addrs/wave
        const float4 wv = wb[(size_t)tt * 16];    // 1KB/wave coalesced
        a.x = fmaf(xv, wv.x, a.x);
        a.y = fmaf(xv, wv.y, a.y);
        a.z = fmaf(xv, wv.z, a.z);
        a.w = fmaf(xv, wv.w, a.w);
    }
    a.x += __shfl_xor(a.x, 16, 64); a.y += __shfl_xor(a.y, 16, 64);
    a.z += __shfl_xor(a.z, 16, 64); a.w += __shfl_xor(a.w, 16, 64);
    a.x += __shfl_xor(a.x, 32, 64); a.y += __shfl_xor(a.y, 32, 64);
    a.z += __shfl_xor(a.z, 32, 64); a.w += __shfl_xor(a.w, 32, 64);

    __shared__ float4 zp[8][16];   // [wave][jq] -> j = jq*4..jq*4+3
    __shared__ float  zs[64];
    if (l < 16) zp[w][jq] = a;
    __syncthreads();

    if (t < BOT) {
        const float* z0 = (const float*)&zp[0][0];   // [w*64 + j]
        float z = rb[t];
#pragma unroll
        for (int wq = 0; wq < 8; ++wq) z += z0[wq * 64 + t];
        zs[t] = z;
        zT[(size_t)t * B_SZ + b] = z;   // transposed: i-major
    }
    __syncthreads();

    if (t < MLP_H) {
        float s = ab1[t];
#pragma unroll
        for (int i = 0; i < BOT; ++i) s = fmaf(zs[i], aw1[i * MLP_H + t], s);
        a4[b * MLP_H + t] = fmaxf(s, 0.f);
    }
}

// ---------------------------------------------------------------------------
// k2: KAN + gate + epilogue. 512 blocks x 512 threads (8 waves).
// Block tile: 16 o x 16 b; wave w = i-chunk of 8. Lane: o_l=l>>2, hq=l&3.
// z-tile (64 i x 16 b, 4KB) staged in LDS; inner loop: 3 float4 weight loads
// + ds_read_b128 z broadcasts + 192 VALU per ii. h-reduce via shfl_xor.
// Gate dot from LDS z; column sums read precomputed (kb2s/gwsum).
// ---------------------------------------------------------------------------
__global__ __launch_bounds__(512) void k2_main(
    const float* __restrict__ zT,
    const float* __restrict__ a4,
    const float* __restrict__ aw2,
    const float* __restrict__ ab2,
    const float* __restrict__ kW1,
    const float* __restrict__ kb1,
    const float* __restrict__ kW2,
    const float* __restrict__ gw,
    const float* __restrict__ gb,
    const float* __restrict__ kb2s,
    const float* __restrict__ gwsum,
    float* __restrict__ out)
{
    __shared__ float zl[BOT][16];        // z-tile: [i][b]
    __shared__ float pK[8][16][24];      // [wave][o][b], padded rows

    const int t    = threadIdx.x;
    const int w    = t >> 6;
    const int lane = t & 63;
    const int o_l  = lane >> 2;
    const int hq   = lane & 3;
    const int o0   = blockIdx.x * 16;
    const int b0   = blockIdx.y * 16;

    // stage full z-tile: 256 threads x one float4 = 64 i-rows x 4 quads.
    if (t < 256) {
        const int i = t >> 2, q = t & 3;
        ((float4*)&zl[i][0])[q] =
            ((const float4*)(zT + (size_t)i * B_SZ + b0))[q];
    }
    __syncthreads();

    float4 acc[16];
#pragma unroll
    for (int b = 0; b < 16; ++b) acc[b] = make_float4(0.f, 0.f, 0.f, 0.f);

    const int i0 = w * 8;
#pragma unroll 2
    for (int ii = 0; ii < 8; ++ii) {
        const int i = i0 + ii;
        const size_t wbo = ((size_t)i * CTX + o0) * KH + (size_t)lane * 4;
        const float4 w1 = *(const float4*)(kW1 + wbo);
        const float4 b1 = *(const float4*)(kb1 + wbo);
        const float4 w2 = *(const float4*)(kW2 + wbo);
        const float4* zr = (const float4*)&zl[i][0];   // LDS broadcast
        const float4 za = zr[0], zb = zr[1], zc = zr[2], zd = zr[3];
        const float zv[16] = { za.x, za.y, za.z, za.w,  zb.x, zb.y, zb.z, zb.w,
                               zc.x, zc.y, zc.z, zc.w,  zd.x, zd.y, zd.z, zd.w };
#pragma unroll
        for (int b = 0; b < 16; ++b) {
            const float z = zv[b];
            float4 hv;
            hv.x = fmaxf(fmaf(z, w1.x, b1.x), 0.f);
            hv.y = fmaxf(fmaf(z, w1.y, b1.y), 0.f);
            hv.z = fmaxf(fmaf(z, w1.z, b1.z), 0.f);
            hv.w = fmaxf(fmaf(z, w1.w, b1.w), 0.f);
            acc[b].x = fmaf(hv.x, w2.x, acc[b].x);
            acc[b].y = fmaf(hv.y, w2.y, acc[b].y);
            acc[b].z = fmaf(hv.z, w2.z, acc[b].z);
            acc[b].w = fmaf(hv.w, w2.w, acc[b].w);
        }
    }

    float aK[16];
#pragma unroll
    for (int b = 0; b < 16; ++b) {
        float s = (acc[b].x + acc[b].y) + (acc[b].z + acc[b].w);
        s += __shfl_xor(s, 1, 64);
        s += __shfl_xor(s, 2, 64);
        aK[b] = s;
    }
    if (hq == 0) {
        float* d = &pK[w][o_l][0];
        ((float4*)d)[0] = make_float4(aK[0],  aK[1],  aK[2],  aK[3]);
        ((float4*)d)[1] = make_float4(aK[4],  aK[5],  aK[6],  aK[7]);
        ((float4*)d)[2] = make_float4(aK[8],  aK[9],  aK[10], aK[11]);
        ((float4*)d)[3] = make_float4(aK[12], aK[13], aK[14], aK[15]);
    }
    __syncthreads();

    // epilogue: t<256 -> (o = t&15, b = t>>4).
    if (t < 256) {
        const int o = t & 15;
        const int b = t >> 4;
        const int oo = o0 + o;
        const int bb = b0 + b;

        float sK = 0.f;
#pragma unroll
        for (int w2 = 0; w2 < 8; ++w2) sK += pK[w2][o][b];

        // gate dot over LDS z; weight gw lane-coalesced 64B segments.
        float sG = 0.f;
#pragma unroll 8
        for (int i = 0; i < BOT; ++i)
            sG = fmaf(zl[i][b], gw[i * CTX + oo], sG);

        sK += kb2s[oo];
        sG += gwsum[oo] + gb[oo];

        const float4 av = *(const float4*)(a4 + bb * MLP_H);
        float ann = ab2[oo];
        ann = fmaf(av.x, aw2[0 * CTX + oo], ann);
        ann = fmaf(av.y, aw2[1 * CTX + oo], ann);
        ann = fmaf(av.z, aw2[2 * CTX + oo], ann);
        ann = fmaf(av.w, aw2[3 * CTX + oo], ann);

        const float g = 1.f / (1.f + __expf(-sG));
        out[(size_t)bb * CTX + oo] = g * ann + (1.f - g) * sK;
    }
}

extern "C" void kernel_launch(void* const* d_in, const int* in_sizes, int n_in,
                              void* d_out, int out_size, void* d_ws, size_t ws_size,
                              hipStream_t stream)
{
    const float* x   = (const float*)d_in[0];
    const float* rw  = (const float*)d_in[1];
    const float* rb  = (const float*)d_in[2];
    const float* aw1 = (const float*)d_in[3];
    const float* ab1 = (const float*)d_in[4];
    const float* aw2 = (const float*)d_in[5];
    const float* ab2 = (const float*)d_in[6];
    const float* kW1 = (const float*)d_in[7];
    const float* kb1 = (const float*)d_in[8];
    const float* kW2 = (const float*)d_in[9];
    const float* kb2 = (const float*)d_in[10];
    const float* gw  = (const float*)d_in[11];
    const float* gb  = (const float*)d_in[12];
    float* out = (float*)d_out;

    // ws layout: zT (64*256) | a4 (256*4) | kb2s (512) | gwsum (512)
    float* zT    = (float*)d_ws;
    float* a4    = zT + (size_t)BOT * B_SZ;
    float* kb2s  = a4 + (size_t)B_SZ * MLP_H;
    float* gwsum = kb2s + CTX;

    kA<<<B_SZ + 8, 512, 0, stream>>>(x, rw, rb, aw1, ab1, kb2, gw,
                                     zT, a4, kb2s, gwsum);
    k2_main<<<dim3(CTX / 16, B_SZ / 16), 512, 0, stream>>>(
        zT, a4, aw2, ab2, kW1, kb1, kW2, gw, gb, kb2s, gwsum, out);
}